// Round 1
// baseline (264.840 us; speedup 1.0000x reference)
//
#include <hip/hip_runtime.h>

// FromRGB fused pipeline:
//   x[8,16,512,512] --(IHT up2 + blur down2 + Haar down2 composed into one
//   separable 4x4 stride-2 stencil)--> new_in[8,16,256,256]
//   new_in --(1x1 conv 16->512, scale 0.25, +bias, leakyrelu(0.2)*sqrt2)--> out[8,512,256,256]
//
// Composed 1D filters (x16), indexed [analysis phi][synthesis f]:
//   (l,l): [1, 7, 7, 1]
//   (l,h): [1, 1,-1,-1]
//   (h,l): [1, 5,-5,-1]
//   (h,h): [1,-1,-1, 1]
// new_in[4*comp+ch] = sum_g s_g * Ty[cY][gY] (x) Tx[cX][gX] applied to
// x[4g+ch] window rows/cols [2o-1 .. 2o+2], all divided by 256.
// comp: 0=ll(cY=0,cX=0) 1=lh(cY=1,cX=0) 2=hl(cY=0,cX=1) 3=hh(cY=1,cX=1)
// group g: 0=ll(gY=0,gX=0,+) 1=lh(gY=1,gX=0,-) 2=hl(gY=0,gX=1,-) 3=hh(gY=1,gX=1,+)

#define H_IN 512
#define W_IN 512
#define H_OUT 256
#define W_OUT 256
#define NB 8
#define C_MID 16
#define C_OUT 512

typedef float fx4 __attribute__((ext_vector_type(4)));

__device__ __forceinline__ float cL(int fsel, float a0, float a1, float a2, float a3) {
  // analysis = l; fsel: 0 -> synth l, 1 -> synth h
  return fsel == 0 ? (a0 + 7.f*a1 + 7.f*a2 + a3) : (a0 + a1 - a2 - a3);
}
__device__ __forceinline__ float cH(int fsel, float a0, float a1, float a2, float a3) {
  // analysis = h
  return fsel == 0 ? (a0 + 5.f*a1 - 5.f*a2 - a3) : (a0 - a1 - a2 + a3);
}

// Stage 1: x -> new_in.  One thread computes a 1(x) x 4(y) strip of outputs
// for one (b, ch): 16 output values (4 comps x 4 rows). Reads a 10-row x 4-col
// window per group (rows shared across the 4 output rows: 10 vs 16 reads).
__global__ __launch_bounds__(256) void k_stage1(const float* __restrict__ x,
                                                float* __restrict__ nin) {
  const int ox = threadIdx.x;        // 0..255
  const int by = blockIdx.x;         // 0..63  (4 output rows each)
  const int bz = blockIdx.y;         // 0..31  = b*4 + ch
  const int b = bz >> 2, ch = bz & 3;
  const int x0 = 2 * ox - 1;
  const int yb = 8 * by - 1;

  float acc[4][4];                   // [comp][row j]
#pragma unroll
  for (int i = 0; i < 4; ++i)
#pragma unroll
    for (int j = 0; j < 4; ++j) acc[i][j] = 0.f;

#pragma unroll
  for (int g = 0; g < 4; ++g) {
    const int gY = g & 1, gX = g >> 1;
    const float sg = (g == 1 || g == 2) ? -1.f : 1.f;
    const float* xp = x + (size_t)(b * 16 + g * 4 + ch) * (H_IN * W_IN);
    float uL[10], uH[10];
#pragma unroll
    for (int t = 0; t < 10; ++t) {
      const int yy = yb + t;
      float r0 = 0.f, r1 = 0.f, r2 = 0.f, r3 = 0.f;
      if (yy >= 0 && yy < H_IN) {     // wave-uniform branch
        const float* row = xp + (size_t)yy * W_IN;
        r0 = (x0 >= 0) ? row[x0] : 0.f;
        r1 = row[x0 + 1];
        r2 = row[x0 + 2];
        r3 = (x0 + 3 < W_IN) ? row[x0 + 3] : 0.f;
      }
      uL[t] = cL(gX, r0, r1, r2, r3);
      uH[t] = cH(gX, r0, r1, r2, r3);
    }
#pragma unroll
    for (int j = 0; j < 4; ++j) {
      const float l0 = uL[2*j], l1 = uL[2*j+1], l2 = uL[2*j+2], l3 = uL[2*j+3];
      const float h0 = uH[2*j], h1 = uH[2*j+1], h2 = uH[2*j+2], h3 = uH[2*j+3];
      acc[0][j] += sg * cL(gY, l0, l1, l2, l3);
      acc[1][j] += sg * cH(gY, l0, l1, l2, l3);
      acc[2][j] += sg * cL(gY, h0, h1, h2, h3);
      acc[3][j] += sg * cH(gY, h0, h1, h2, h3);
    }
  }

#pragma unroll
  for (int comp = 0; comp < 4; ++comp)
#pragma unroll
    for (int j = 0; j < 4; ++j) {
      const int oy = 4 * by + j;
      nin[((size_t)(b * 16 + comp * 4 + ch) * H_OUT + oy) * W_OUT + ox] =
          acc[comp][j] * (1.f / 256.f);
    }
}

// Stage 2: 1x1 conv 16->512 + bias + leakyrelu*sqrt2.
// Block = 256 threads covering 4 rows x 256 cols of one image b (each thread
// owns one float4 of x positions). Weights pre-scaled by 0.25 in LDS
// (broadcast reads). Streams 512 non-temporal float4 stores per thread.
__global__ __launch_bounds__(256) void k_stage2(const float* __restrict__ nin,
                                                const float* __restrict__ w,
                                                const float* __restrict__ bias,
                                                float* __restrict__ out) {
  __shared__ float ws[C_OUT * 16];
  __shared__ float bs[C_OUT];
  const int t = threadIdx.x;
#pragma unroll
  for (int i = 0; i < 32; ++i) ws[t + 256 * i] = w[t + 256 * i] * 0.25f;
  bs[t] = bias[t];
  bs[t + 256] = bias[t + 256];
  __syncthreads();

  const int by = blockIdx.x;                 // 0..63
  const int b  = blockIdx.y;                 // 0..7
  const int y  = 4 * by + (t >> 6);
  const int xq = (t & 63) * 4;

  const float* np = nin + ((size_t)(b * C_MID) * H_OUT + y) * W_OUT + xq;
  fx4 v[16];
#pragma unroll
  for (int c = 0; c < 16; ++c)
    v[c] = *reinterpret_cast<const fx4*>(np + (size_t)c * (H_OUT * W_OUT));

  float* op = out + ((size_t)(b * C_OUT) * H_OUT + y) * W_OUT + xq;
  const float s2 = 1.41421356237309515f;
#pragma unroll 2
  for (int o = 0; o < C_OUT; ++o) {
    const float* wr = &ws[o * 16];
    const float bo = bs[o];
    float ax = bo, ay = bo, az = bo, aw = bo;
#pragma unroll
    for (int c = 0; c < 16; ++c) {
      const float wc = wr[c];
      ax = fmaf(wc, v[c].x, ax);
      ay = fmaf(wc, v[c].y, ay);
      az = fmaf(wc, v[c].z, az);
      aw = fmaf(wc, v[c].w, aw);
    }
    ax = (ax >= 0.f ? ax : 0.2f * ax) * s2;
    ay = (ay >= 0.f ? ay : 0.2f * ay) * s2;
    az = (az >= 0.f ? az : 0.2f * az) * s2;
    aw = (aw >= 0.f ? aw : 0.2f * aw) * s2;
    fx4 r; r.x = ax; r.y = ay; r.z = az; r.w = aw;
    __builtin_nontemporal_store(r,
        reinterpret_cast<fx4*>(op + (size_t)o * (H_OUT * W_OUT)));
  }
}

extern "C" void kernel_launch(void* const* d_in, const int* in_sizes, int n_in,
                              void* d_out, int out_size, void* d_ws, size_t ws_size,
                              hipStream_t stream) {
  const float* x    = (const float*)d_in[0];
  const float* w    = (const float*)d_in[1];
  const float* bias = (const float*)d_in[2];
  float* nin = (float*)d_out;                                  // output 0
  float* out = (float*)d_out + (size_t)NB * C_MID * H_OUT * W_OUT;  // output 1

  k_stage1<<<dim3(64, 32), dim3(256), 0, stream>>>(x, nin);
  k_stage2<<<dim3(64, 8), dim3(256), 0, stream>>>(nin, w, bias, out);
}

// Round 2
// 257.385 us; speedup vs baseline: 1.0290x; 1.0290x over previous
//
#include <hip/hip_runtime.h>

// FromRGB fused pipeline:
//   x[8,16,512,512] --(IHT up2 + blur down2 + Haar down2 composed into one
//   separable 4x4 stride-2 stencil)--> new_in[8,16,256,256]
//   new_in --(1x1 conv 16->512, scale 0.25, +bias, leakyrelu(0.2)*sqrt2)--> out[8,512,256,256]
//
// Composed 1D filters (x16), indexed [analysis][synthesis]:
//   (l,l): [1, 7, 7, 1]   (l,h): [1, 1,-1,-1]
//   (h,l): [1, 5,-5,-1]   (h,h): [1,-1,-1, 1]
// new_in[4*comp+ch](oy,ox) = (1/256) * sum_g s_g *
//     [y-filter(comp,gY) (x) x-filter(comp,gX)] . x[4g+ch][2oy-1..2oy+2][2ox-1..2ox+2]
// comp: 0=ll 1=lh 2=hl 3=hh ; g: 0=ll(+) 1=lh(-) 2=hl(-) 3=hh(+)

#define H_IN 512
#define W_IN 512
#define H_OUT 256
#define W_OUT 256
#define NB 8
#define C_MID 16
#define C_OUT 512

typedef float fx4 __attribute__((ext_vector_type(4)));

__device__ __forceinline__ float cL(int fsel, float a0, float a1, float a2, float a3) {
  // analysis = l; fsel 0 -> [1,7,7,1], 1 -> [1,1,-1,-1]
  return fsel == 0 ? (a0 + 7.f*a1 + 7.f*a2 + a3) : (a0 + a1 - a2 - a3);
}
__device__ __forceinline__ float cH(int fsel, float a0, float a1, float a2, float a3) {
  // analysis = h; fsel 0 -> [1,5,-5,-1], 1 -> [1,-1,-1,1]
  return fsel == 0 ? (a0 + 5.f*a1 - 5.f*a2 - a3) : (a0 - a1 - a2 + a3);
}

// Stage 1: x -> new_in. One thread computes a 4x(x) by 4(y) block of outputs
// for one (b, ch): 64 values (4 comps x 4 rows x 4 cols). Row loads are
// 1 scalar + 3 aligned float4 (12 cols) instead of 16 scalar loads.
__global__ __launch_bounds__(256) void k_stage1(const float* __restrict__ x,
                                                float* __restrict__ nin) {
  const int t  = threadIdx.x;
  const int q  = t & 63;                       // x-quad: output cols 4q..4q+3
  const int rq = blockIdx.x * 4 + (t >> 6);    // row-quad: output rows 4rq..4rq+3
  const int bz = blockIdx.y;                   // b*4 + ch
  const int b = bz >> 2, ch = bz & 3;
  const int yb = 8 * rq - 1;

  // y-combination weights: WL = "L" output filter, WH = "H" output filter,
  // selected by gY (the group's y analysis phase).
  const float WL[2][4] = {{1.f, 7.f, 7.f, 1.f}, {1.f, 1.f, -1.f, -1.f}};
  const float WH[2][4] = {{1.f, 5.f, -5.f, -1.f}, {1.f, -1.f, -1.f, 1.f}};

  float acc[4][4][4];                          // [comp][row j][col xo]
#pragma unroll
  for (int i = 0; i < 4; ++i)
#pragma unroll
    for (int j = 0; j < 4; ++j)
#pragma unroll
      for (int k = 0; k < 4; ++k) acc[i][j][k] = 0.f;

#pragma unroll
  for (int g = 0; g < 4; ++g) {
    const int gY = g & 1, gX = g >> 1;
    const float sg = (g == 1 || g == 2) ? -1.f : 1.f;
    const float* xp = x + (size_t)(b * 16 + g * 4 + ch) * (H_IN * W_IN);
#pragma unroll
    for (int tt = 0; tt < 10; ++tt) {
      const int yy = yb + tt;
      if (yy < 0 || yy >= H_IN) continue;      // wave-uniform (rq uniform per wave)
      const float* row = xp + (size_t)yy * W_IN + 8 * q;
      float c[12];                             // cols 8q-1 .. 8q+10
      c[0] = (q > 0) ? row[-1] : 0.f;
      const fx4 m0 = *reinterpret_cast<const fx4*>(row);
      const fx4 m1 = *reinterpret_cast<const fx4*>(row + 4);
      c[1] = m0.x; c[2] = m0.y; c[3] = m0.z; c[4] = m0.w;
      c[5] = m1.x; c[6] = m1.y; c[7] = m1.z; c[8] = m1.w;
      if (q < 63) {
        const fx4 m2 = *reinterpret_cast<const fx4*>(row + 8);
        c[9] = m2.x; c[10] = m2.y; c[11] = m2.z;
      } else {
        c[9] = 0.f; c[10] = 0.f; c[11] = 0.f;
      }
      float vL[4], vH[4];
#pragma unroll
      for (int xo = 0; xo < 4; ++xo) {
        const float a0 = c[2*xo], a1 = c[2*xo+1], a2 = c[2*xo+2], a3 = c[2*xo+3];
        vL[xo] = cL(gX, a0, a1, a2, a3);
        vH[xo] = cH(gX, a0, a1, a2, a3);
      }
#pragma unroll
      for (int j = 0; j < 4; ++j) {
        const int p = tt - 2 * j;              // compile-time; dead branches fold
        if (p < 0 || p > 3) continue;
        const float wl = sg * WL[gY][p];
        const float wh = sg * WH[gY][p];
#pragma unroll
        for (int xo = 0; xo < 4; ++xo) {
          acc[0][j][xo] = fmaf(wl, vL[xo], acc[0][j][xo]);
          acc[1][j][xo] = fmaf(wh, vL[xo], acc[1][j][xo]);
          acc[2][j][xo] = fmaf(wl, vH[xo], acc[2][j][xo]);
          acc[3][j][xo] = fmaf(wh, vH[xo], acc[3][j][xo]);
        }
      }
    }
  }

  const float inv = 1.f / 256.f;
#pragma unroll
  for (int comp = 0; comp < 4; ++comp)
#pragma unroll
    for (int j = 0; j < 4; ++j) {
      fx4 r;
      r.x = acc[comp][j][0] * inv; r.y = acc[comp][j][1] * inv;
      r.z = acc[comp][j][2] * inv; r.w = acc[comp][j][3] * inv;
      *reinterpret_cast<fx4*>(
          nin + ((size_t)(b * 16 + comp * 4 + ch) * H_OUT + 4 * rq + j) * W_OUT + 4 * q) = r;
    }
}

__device__ __forceinline__ fx4 vfma(fx4 v, float s, fx4 a) {
  a.x = fmaf(v.x, s, a.x); a.y = fmaf(v.y, s, a.y);
  a.z = fmaf(v.z, s, a.z); a.w = fmaf(v.w, s, a.w);
  return a;
}

// Stage 2: 1x1 conv 16->512 + bias + leakyrelu*sqrt2, channel-chunked 4-way
// for occupancy (16 waves/CU). Weights (pre-scaled 0.25) in LDS as float4
// (broadcast ds_read_b128). Each thread owns 4 x positions of one row and
// streams 128 non-temporal float4 stores.
__global__ __launch_bounds__(256) void k_stage2(const float* __restrict__ nin,
                                                const float* __restrict__ w,
                                                const float* __restrict__ bias,
                                                float* __restrict__ out) {
  __shared__ fx4 ws4[128 * 4];
  __shared__ float bs[128];
  const int t = threadIdx.x;
  const int chunk = blockIdx.z;                // 0..3 -> channels 128*chunk..+127
  const int obase = 128 * chunk;

  const fx4* w4 = reinterpret_cast<const fx4*>(w + (size_t)obase * 16);
  ws4[t]       = w4[t] * 0.25f;
  ws4[t + 256] = w4[t + 256] * 0.25f;
  if (t < 128) bs[t] = bias[obase + t];
  __syncthreads();

  const int by = blockIdx.x;                   // 0..63
  const int b  = blockIdx.y;                   // 0..7
  const int y  = 4 * by + (t >> 6);
  const int xq = (t & 63) * 4;

  const float* np = nin + ((size_t)(b * C_MID) * H_OUT + y) * W_OUT + xq;
  fx4 v[16];
#pragma unroll
  for (int c = 0; c < 16; ++c)
    v[c] = *reinterpret_cast<const fx4*>(np + (size_t)c * (H_OUT * W_OUT));

  float* op = out + ((size_t)(b * C_OUT + obase) * H_OUT + y) * W_OUT + xq;
  const float s2 = 1.41421356237309515f;
#pragma unroll 2
  for (int o = 0; o < 128; ++o) {
    const fx4 w0 = ws4[4*o], w1 = ws4[4*o+1], w2 = ws4[4*o+2], w3 = ws4[4*o+3];
    const float bo = bs[o];
    fx4 a; a.x = bo; a.y = bo; a.z = bo; a.w = bo;
    a = vfma(v[0],  w0.x, a); a = vfma(v[1],  w0.y, a);
    a = vfma(v[2],  w0.z, a); a = vfma(v[3],  w0.w, a);
    a = vfma(v[4],  w1.x, a); a = vfma(v[5],  w1.y, a);
    a = vfma(v[6],  w1.z, a); a = vfma(v[7],  w1.w, a);
    a = vfma(v[8],  w2.x, a); a = vfma(v[9],  w2.y, a);
    a = vfma(v[10], w2.z, a); a = vfma(v[11], w2.w, a);
    a = vfma(v[12], w3.x, a); a = vfma(v[13], w3.y, a);
    a = vfma(v[14], w3.z, a); a = vfma(v[15], w3.w, a);
    a.x = (a.x >= 0.f ? a.x : 0.2f * a.x) * s2;
    a.y = (a.y >= 0.f ? a.y : 0.2f * a.y) * s2;
    a.z = (a.z >= 0.f ? a.z : 0.2f * a.z) * s2;
    a.w = (a.w >= 0.f ? a.w : 0.2f * a.w) * s2;
    __builtin_nontemporal_store(a,
        reinterpret_cast<fx4*>(op + (size_t)o * (H_OUT * W_OUT)));
  }
}

extern "C" void kernel_launch(void* const* d_in, const int* in_sizes, int n_in,
                              void* d_out, int out_size, void* d_ws, size_t ws_size,
                              hipStream_t stream) {
  const float* x    = (const float*)d_in[0];
  const float* w    = (const float*)d_in[1];
  const float* bias = (const float*)d_in[2];
  float* nin = (float*)d_out;                                       // output 0
  float* out = (float*)d_out + (size_t)NB * C_MID * H_OUT * W_OUT;  // output 1

  k_stage1<<<dim3(16, 32), dim3(256), 0, stream>>>(x, nin);
  k_stage2<<<dim3(64, 8, 4), dim3(256), 0, stream>>>(nin, w, bias, out);
}